// Round 7
// baseline (86.920 us; speedup 1.0000x reference)
//
#include <hip/hip_runtime.h>

#define EPS_C 0.0009f   // 0.03^2

__device__ __forceinline__ float metric_val(float dot, float f, float g) {
    float c    = dot / (f * g);
    float dn   = sqrtf(fmaxf(2.0f - 2.0f * c, 0.0f));
    float dist = (2.0f - dn) * 0.5f;
    float lum  = (2.0f * f * g + EPS_C) / (f * f + g * g + EPS_C);
    float met  = dist * sqrtf(lum);
    return (1.0f - met) * 2.0f;
}

// Single-node graph, no cooperative launch, no contended atomics.
// Phase 1 = R2's measured-fastest structure: 256 blocks x 256 threads,
//   bg = blockIdx >> 5 (8 groups of 8 batch rows; wave w owns b = bg*8+2w, +1)
//   mg = blockIdx & 31 (32 groups of 8 modes; same-mg blocks XCD-affine)
// Cross-block min: each block writes its 8 partials to ws[b*32+mg] with
// agent-scope atomic stores (coherent across XCD L2s), fences, then sets
// flags[blockIdx]=1 (agent scope). Block 0's 256 threads each poll one flag
// (grid == 256 <= CU count -> all blocks co-resident -> no deadlock; flags
// are 0xAA-poison or 0 before the call, never 1), then 64 threads fold 32
// contiguous partials each and write out directly.
// R5 post-mortem: atomicMin/CAS onto out's 4 cache lines cost ~40 us of
// serialization -- this scheme has zero same-line RMW contention.
__global__ __launch_bounds__(256, 1)
void simk_fused(const float* __restrict__ inputs, const float* __restrict__ modes,
                float* __restrict__ ws, float* __restrict__ out) {
    const int tid  = threadIdx.x;
    const int lane = tid & 63;
    const int w    = tid >> 6;
    const int bg   = blockIdx.x >> 5;
    const int mg   = blockIdx.x & 31;
    const int b0   = bg * 8 + w * 2;
    const int b1   = b0 + 1;

    unsigned int* flags = (unsigned int*)(ws + 2048);   // 256 flags after partials

    const float4* inp4 = (const float4*)inputs;
    const float4* mod4 = (const float4*)modes;

    // Input rows: float4 index = j*64 + lane (coalesced 1KB/step)
    float4 in0[16], in1[16];
#pragma unroll
    for (int j = 0; j < 16; ++j) in0[j] = inp4[(size_t)b0 * 1024 + j * 64 + lane];
#pragma unroll
    for (int j = 0; j < 16; ++j) in1[j] = inp4[(size_t)b1 * 1024 + j * 64 + lane];

    // Input Frobenius norms
    float s0 = 0.f, s1 = 0.f;
#pragma unroll
    for (int j = 0; j < 16; ++j) {
        s0 += in0[j].x * in0[j].x + in0[j].y * in0[j].y + in0[j].z * in0[j].z + in0[j].w * in0[j].w;
        s1 += in1[j].x * in1[j].x + in1[j].y * in1[j].y + in1[j].z * in1[j].z + in1[j].w * in1[j].w;
    }
#pragma unroll
    for (int sh = 1; sh < 64; sh <<= 1) {
        s0 += __shfl_xor(s0, sh, 64);
        s1 += __shfl_xor(s1, sh, 64);
    }
    const float f0 = sqrtf(s0);
    const float f1 = sqrtf(s1);

    float min0 = 3.0e38f, min1 = 3.0e38f;

    for (int mi = 0; mi < 8; ++mi) {
        const int m = mg * 8 + mi;
        const float4* mp = mod4 + (size_t)m * 1024;

        // 12 independent FMA chains for ILP
        float d0x = 0.f, d0y = 0.f, d0z = 0.f, d0w = 0.f;
        float d1x = 0.f, d1y = 0.f, d1z = 0.f, d1w = 0.f;
        float qx  = 0.f, qy  = 0.f, qz  = 0.f, qw  = 0.f;
#pragma unroll
        for (int j = 0; j < 16; ++j) {
            float4 v = mp[j * 64 + lane];
            d0x += v.x * in0[j].x; d0y += v.y * in0[j].y;
            d0z += v.z * in0[j].z; d0w += v.w * in0[j].w;
            d1x += v.x * in1[j].x; d1y += v.y * in1[j].y;
            d1z += v.z * in1[j].z; d1w += v.w * in1[j].w;
            qx  += v.x * v.x;      qy  += v.y * v.y;
            qz  += v.z * v.z;      qw  += v.w * v.w;
        }
        float d0 = (d0x + d0y) + (d0z + d0w);
        float d1 = (d1x + d1y) + (d1z + d1w);
        float q  = (qx + qy) + (qz + qw);
#pragma unroll
        for (int sh = 1; sh < 64; sh <<= 1) {
            d0 += __shfl_xor(d0, sh, 64);
            d1 += __shfl_xor(d1, sh, 64);
            q  += __shfl_xor(q,  sh, 64);
        }
        const float g = sqrtf(q);
        min0 = fminf(min0, metric_val(d0, f0, g));
        min1 = fminf(min1, metric_val(d1, f1, g));
    }

    // Publish partials at device (agent) scope: coherent across XCD L2s.
    if (lane == 0) {
        __hip_atomic_store(&ws[b0 * 32 + mg], min0, __ATOMIC_RELAXED, __HIP_MEMORY_SCOPE_AGENT);
        __hip_atomic_store(&ws[b1 * 32 + mg], min1, __ATOMIC_RELAXED, __HIP_MEMORY_SCOPE_AGENT);
    }
    __threadfence();     // order partial stores before the flag store
    __syncthreads();     // all 4 waves' stores+fences complete before signal

    if (tid == 0)
        __hip_atomic_store(&flags[blockIdx.x], 1u, __ATOMIC_RELEASE, __HIP_MEMORY_SCOPE_AGENT);

    if (blockIdx.x == 0) {
        // Thread i polls flag i. Flags are 0xAAAAAAAA (poison) or 0 before
        // this call -- never 1 -- so no stale pass-through.
        while (__hip_atomic_load(&flags[tid], __ATOMIC_ACQUIRE, __HIP_MEMORY_SCOPE_AGENT) != 1u)
            __builtin_amdgcn_s_sleep(1);
        __syncthreads();
        __threadfence();
        if (tid < 64) {
            // Fold 32 contiguous partials for batch row = tid.
            float m = 3.0e38f;
#pragma unroll
            for (int mg2 = 0; mg2 < 32; ++mg2)
                m = fminf(m, __hip_atomic_load(&ws[tid * 32 + mg2],
                                               __ATOMIC_RELAXED, __HIP_MEMORY_SCOPE_AGENT));
            out[tid] = m;
        }
    }
}

extern "C" void kernel_launch(void* const* d_in, const int* in_sizes, int n_in,
                              void* d_out, int out_size, void* d_ws, size_t ws_size,
                              hipStream_t stream) {
    const float* inputs = (const float*)d_in[0];
    const float* modes  = (const float*)d_in[1];
    float* ws  = (float*)d_ws;
    float* out = (float*)d_out;

    simk_fused<<<256, 256, 0, stream>>>(inputs, modes, ws, out);
}